// Round 4
// baseline (240.558 us; speedup 1.0000x reference)
//
#include <hip/hip_runtime.h>
#include <hip/hip_bf16.h>
#include <math.h>

#define B_ 32
#define T_ 2000
#define DE_ 512
#define DD_ 1024
#define A_ 128
#define FN_ 32
#define FS_ 16
#define KW_ (2*FS_+1)   // 33

typedef __bf16 bf16x8 __attribute__((ext_vector_type(8)));
typedef __bf16 bf16x4 __attribute__((ext_vector_type(4)));
typedef float f32x4 __attribute__((ext_vector_type(4)));

#define BT 256           // t-rows per score block (16 waves x 16 rows)
#define LSTR 40          // loc tile LDS stride (bf16)

// async global->LDS, 16 B per lane; dest = lds base (wave-uniform) + lane*16
__device__ __forceinline__ void load_lds16(const void* g, void* l) {
    __builtin_amdgcn_global_load_lds(
        (const __attribute__((address_space(1))) unsigned int*)g,
        (__attribute__((address_space(3))) unsigned int*)l, 16, 0, 0);
}

__device__ __forceinline__ bf16x8 cvt8(float4 x, float4 y) {
    bf16x8 o;
    o[0] = (__bf16)x.x; o[1] = (__bf16)x.y; o[2] = (__bf16)x.z; o[3] = (__bf16)x.w;
    o[4] = (__bf16)y.x; o[5] = (__bf16)y.y; o[6] = (__bf16)y.z; o[7] = (__bf16)y.w;
    return o;
}

// ---------------------------------------------------------------------------
// Kernel 1: prep.
//  blocks   0..63 : enc_w/att_w fp32->bf16
//  blocks  64..191: pdec[b][a] = att_b[a] + input_dec[b] . dec_w[a]
//  blocks 192..208: zero ctx_un (16384 f) + denom (32 f)
// ---------------------------------------------------------------------------
__global__ __launch_bounds__(256) void prep_kernel(
    const float* __restrict__ enc_w, const float* __restrict__ att_w,
    const float* __restrict__ input_dec, const float* __restrict__ dec_w,
    const float* __restrict__ att_b,
    __bf16* __restrict__ enc_bf, __bf16* __restrict__ att_bf,
    float* __restrict__ pdec, float* __restrict__ ctx_un /* denom follows */)
{
    int bx = blockIdx.x, tid = threadIdx.x;
    if (bx < 64) {
        int i = bx * 256 + tid;                         // float4 index
        float4 v = ((const float4*)enc_w)[i];
        bf16x4 o;
        o[0] = (__bf16)v.x; o[1] = (__bf16)v.y; o[2] = (__bf16)v.z; o[3] = (__bf16)v.w;
        *(bf16x4*)(enc_bf + (size_t)i * 4) = o;
        if (i < (A_ * FN_) / 4) {
            float4 w = ((const float4*)att_w)[i];
            bf16x4 p;
            p[0] = (__bf16)w.x; p[1] = (__bf16)w.y; p[2] = (__bf16)w.z; p[3] = (__bf16)w.w;
            *(bf16x4*)(att_bf + (size_t)i * 4) = p;
        }
    } else if (bx < 192) {
        int pb = bx - 64;                               // 0..127
        int b  = pb >> 2;
        int a0 = (pb & 3) * 32;
        int al = tid >> 3;                              // 0..31
        int kg = tid & 7;                               // 0..7
        int a  = a0 + al;
        const float4* w = (const float4*)(dec_w + (size_t)a * DD_);
        const float4* x = (const float4*)(input_dec + (size_t)b * DD_);
        float acc = 0.f;
        #pragma unroll 8
        for (int j = 0; j < 32; j++) {
            int i4 = kg + j * 8;
            float4 wv = w[i4], xv = x[i4];
            acc += wv.x * xv.x + wv.y * xv.y + wv.z * xv.z + wv.w * xv.w;
        }
        acc += __shfl_xor(acc, 1, 64);
        acc += __shfl_xor(acc, 2, 64);
        acc += __shfl_xor(acc, 4, 64);
        if (kg == 0) pdec[b * A_ + a] = acc + att_b[a];
    } else {
        int idx = (bx - 192) * 256 + tid;               // float4 index
        if (idx < (B_ * DE_ + B_) / 4 + 1)              // 16416 floats -> 4104 f4
            ((float4*)ctx_un)[idx] = make_float4(0.f, 0.f, 0.f, 0.f);
    }
}

// ---------------------------------------------------------------------------
// Kernel 2: score + context partials. One block = (b, 256 t-rows), 1024 thr
// = 16 waves, ONE block per CU (LDS 153.7 KB of the 160 KiB).
// The ENTIRE B matrix (enc_bf, 128x512 bf16 = 131 KB) is staged into LDS
// once at block start (8 chunks, XOR-swizzled). The K-loop then has ZERO
// barriers: each wave free-runs its A-stream (HBM) + ds_read + MFMA, so
// the 16 staggered waves/CU hide HBM latency by TLP instead of being
// lockstepped onto the slowest load by per-iteration __syncthreads vmcnt(0)
// drains (the structural stall of rounds 0-3).
// Conv register-blocked as before. Max-free softmax: w = exp(score - M),
// M = sum|out_w|. Block accumulates its 256x512 tile into ctx_un + denom.
// ---------------------------------------------------------------------------
__global__ __launch_bounds__(1024, 4) void score_kernel(
    const float* __restrict__ input_enc, const __bf16* __restrict__ enc_bf,
    const float* __restrict__ prev_att,  const float* __restrict__ conv_w,
    const __bf16* __restrict__ att_bf,   const float* __restrict__ pdec,
    const float* __restrict__ out_w,     const int* __restrict__ lengths,
    float* __restrict__ wbuf, float* __restrict__ ctx_un,
    float* __restrict__ denom)
{
    __shared__ __align__(16) char Bt[8][16384];  // full B: 8 chunks x (128 rows x 64 k bf16)
    __shared__ __align__(16) float pa_s[BT + 2 * FS_];
    __shared__ __align__(16) __bf16 loc_s[BT * LSTR];
    __shared__ float w_s[BT];

    const int tid  = threadIdx.x;
    const int lane = tid & 63;
    const int wv   = tid >> 6;                   // 0..15
    const int b  = blockIdx.y;
    const int t0 = blockIdx.x * BT;
    const int len = lengths[b];

    // ---- stage ALL of B into LDS (async), 8 lds16 per thread
    #pragma unroll
    for (int j = 0; j < 8; j++) {
        int w  = wv * 64 + lane;                 // 0..1023 slot within chunk
        int r  = w >> 3;                         // row 0..127
        int cp = w & 7;                          // phys 16B slot in row
        int c  = cp ^ (r & 7);                   // XOR bank swizzle (source side)
        load_lds16(enc_bf + (size_t)r * DE_ + j * 64 + c * 8,
                   Bt[j] + wv * 1024);
    }

    // conv weights for this thread's filter f: direct from global (L1-hot)
    const int f    = tid & 31;
    const int rblk = tid >> 5;                   // 0..31 -> rows rblk*8..rblk*8+7
    float cwr[KW_];
    #pragma unroll
    for (int k = 0; k < KW_; k++) cwr[k] = conv_w[f * KW_ + k];

    if (tid < BT + 2 * FS_) {
        int t = t0 - FS_ + tid;
        pa_s[tid] = (t >= 0 && t < T_) ? prev_att[b * T_ + t] : 0.f;
    }
    __syncthreads();                             // pa_s ready; B-stage drained

    {   // conv -> loc (bf16), register-blocked: 8 consecutive rows per thread
        float par[40];
        #pragma unroll
        for (int j = 0; j < 10; j++)
            *(float4*)&par[j * 4] = *(const float4*)&pa_s[rblk * 8 + j * 4];
        float accv[8] = {0.f, 0.f, 0.f, 0.f, 0.f, 0.f, 0.f, 0.f};
        #pragma unroll
        for (int k = 0; k < KW_; k++) {
            float c = cwr[k];
            #pragma unroll
            for (int j = 0; j < 8; j++) accv[j] += par[j + k] * c;
        }
        #pragma unroll
        for (int j = 0; j < 8; j++)
            loc_s[(rblk * 8 + j) * LSTR + f] = (__bf16)accv[j];
    }
    __syncthreads();                             // loc_s ready

    const int col  = lane & 15;
    const int grp  = lane >> 4;
    const int rowb = wv * 16 + col;              // 0..255
    const int t_row = t0 + rowb;
    const int t_clamp = t_row < T_ ? t_row : T_ - 1;
    const int sw = (col & 7);                    // XOR swizzle key for ds reads

    f32x4 acc[8];
    const f32x4 zero = (f32x4){0.f, 0.f, 0.f, 0.f};

    {   // loc-projection MFMA (K=32=FN)
        bf16x8 afrag = *(const bf16x8*)(loc_s + rowb * LSTR + grp * 8);
        #pragma unroll
        for (int i = 0; i < 8; i++) {
            bf16x8 bfrag = *(const bf16x8*)(att_bf + (size_t)(i * 16 + col) * FN_ + grp * 8);
            acc[i] = __builtin_amdgcn_mfma_f32_16x16x32_bf16(afrag, bfrag, zero, 0, 0, 0);
        }
    }

    const float* arow = input_enc + ((size_t)(b * T_ + t_clamp)) * DE_ + grp * 8;

    // ---- barrier-free K-loop: A stream + LDS-resident B + MFMA
    #pragma unroll
    for (int it = 0; it < 8; ++it) {
        const int kc = it * 64;
        float4 r0 = *(const float4*)(arow + kc);
        float4 r1 = *(const float4*)(arow + kc + 4);
        float4 r2 = *(const float4*)(arow + kc + 32);
        float4 r3 = *(const float4*)(arow + kc + 36);
        bf16x8 af0 = cvt8(r0, r1);
        bf16x8 af1 = cvt8(r2, r3);

        #pragma unroll
        for (int i = 0; i < 8; i++) {
            bf16x8 bfrag = *(const bf16x8*)(Bt[it] + (i * 16 + col) * 128 + ((grp ^ sw) * 16));
            acc[i] = __builtin_amdgcn_mfma_f32_16x16x32_bf16(af0, bfrag, acc[i], 0, 0, 0);
        }
        #pragma unroll
        for (int i = 0; i < 8; i++) {
            bf16x8 bfrag = *(const bf16x8*)(Bt[it] + (i * 16 + col) * 128 + (((4 + grp) ^ sw) * 16));
            acc[i] = __builtin_amdgcn_mfma_f32_16x16x32_bf16(af1, bfrag, acc[i], 0, 0, 0);
        }
    }

    // epilogue: s = tanh(acc + bias) . out_w over a; M = sum|out_w|
    float s[4] = {0.f, 0.f, 0.f, 0.f};
    float Mabs = 0.f;
    #pragma unroll
    for (int i = 0; i < 8; i++) {
        int a = i * 16 + col;
        float ow = out_w[a];
        Mabs += fabsf(ow);
        float bias = pdec[b * A_ + a];
        #pragma unroll
        for (int r = 0; r < 4; r++) {
            float v = acc[i][r] + bias;
            v = fminf(fmaxf(v, -15.f), 15.f);
            float e = __expf(2.f * v);
            s[r] += ow * ((e - 1.f) / (e + 1.f));
        }
    }
    #pragma unroll
    for (int r = 0; r < 4; r++) {
        s[r] += __shfl_xor(s[r], 1, 64);
        s[r] += __shfl_xor(s[r], 2, 64);
        s[r] += __shfl_xor(s[r], 4, 64);
        s[r] += __shfl_xor(s[r], 8, 64);
    }
    Mabs += __shfl_xor(Mabs, 1, 64);
    Mabs += __shfl_xor(Mabs, 2, 64);
    Mabs += __shfl_xor(Mabs, 4, 64);
    Mabs += __shfl_xor(Mabs, 8, 64);    // same value & rounding in every wave

    if (col == 0) {
        #pragma unroll
        for (int r = 0; r < 4; r++) {
            int rl = wv * 16 + grp * 4 + r;
            int t = t0 + rl;
            float w = 0.f;
            if (t < len) w = __expf(s[r] - Mabs);
            w_s[rl] = w;
            if (t < T_) wbuf[b * T_ + t] = w;
        }
    }
    __syncthreads();                             // w_s ready

    // denominator partial (wave 0 reduces all 256)
    if (tid < 64) {
        float w = w_s[tid] + w_s[tid + 64] + w_s[tid + 128] + w_s[tid + 192];
        w += __shfl_xor(w, 1, 64);
        w += __shfl_xor(w, 2, 64);
        w += __shfl_xor(w, 4, 64);
        w += __shfl_xor(w, 8, 64);
        w += __shfl_xor(w, 16, 64);
        w += __shfl_xor(w, 32, 64);
        if (tid == 0) atomicAdd(&denom[b], w);
    }

    // context partial: 4 row-groups x 256 threads (2 d-cols each); tile L2/L3-hot
    int n_eff = len - t0;
    if (n_eff > BT) n_eff = BT;
    if (n_eff > 0) {
        int rg  = tid >> 8;                      // 0..3
        int d0  = (tid & 255) * 2;
        int rlo = rg * 64;
        int rhi = rlo + 64 < n_eff ? rlo + 64 : n_eff;
        if (rhi > rlo) {
            const float* ebase = input_enc + ((size_t)(b * T_ + t0 + rlo)) * DE_ + d0;
            float cx = 0.f, cy = 0.f;
            #pragma unroll 8
            for (int r = 0; r < rhi - rlo; r++) {
                float w = w_s[rlo + r];
                float2 v = *(const float2*)(ebase + (size_t)r * DE_);
                cx += w * v.x;
                cy += w * v.y;
            }
            atomicAdd(&ctx_un[b * DE_ + d0 + 0], cx);
            atomicAdd(&ctx_un[b * DE_ + d0 + 1], cy);
        }
    }
}

// ---------------------------------------------------------------------------
// Kernel 3: finalize. blocks 0..63: att = wbuf/denom; 64..79: ctx = ctx_un/denom
// ---------------------------------------------------------------------------
__global__ __launch_bounds__(256) void finalize_kernel(
    const float* __restrict__ wbuf, const float* __restrict__ ctx_un,
    const float* __restrict__ denom, float* __restrict__ out)
{
    int bx = blockIdx.x, tid = threadIdx.x;
    if (bx < 64) {
        int i4 = bx * 256 + tid;
        if (i4 < (B_ * T_) / 4) {
            int b = i4 / (T_ / 4);
            float inv = 1.f / denom[b];
            float4 w = ((const float4*)wbuf)[i4];
            w.x *= inv; w.y *= inv; w.z *= inv; w.w *= inv;
            ((float4*)(out + B_ * DE_))[i4] = w;
        }
    } else {
        int j = (bx - 64) * 256 + tid;          // 0..4095
        int b = j / (DE_ / 4);
        float inv = 1.f / denom[b];
        float4 c = ((const float4*)ctx_un)[j];
        c.x *= inv; c.y *= inv; c.z *= inv; c.w *= inv;
        ((float4*)out)[j] = c;
    }
}

// ---------------------------------------------------------------------------
extern "C" void kernel_launch(void* const* d_in, const int* in_sizes, int n_in,
                              void* d_out, int out_size, void* d_ws, size_t ws_size,
                              hipStream_t stream)
{
    const float* input_enc   = (const float*)d_in[0];
    const int*   enc_lengths = (const int*)d_in[1];
    const float* input_dec   = (const float*)d_in[2];
    const float* prev_att    = (const float*)d_in[3];
    const float* conv_w      = (const float*)d_in[4];
    const float* enc_w       = (const float*)d_in[5];
    const float* dec_w       = (const float*)d_in[6];
    const float* att_w       = (const float*)d_in[7];
    const float* att_b       = (const float*)d_in[8];
    const float* out_w       = (const float*)d_in[9];

    float* out = (float*)d_out;                 // [0:B*DE) context, [B*DE:) att_weight
    char* ws = (char*)d_ws;
    float*  pdec   = (float*)ws;                              // 4096 f   (16384 B)
    float*  wbuf   = (float*)(ws + 16384);                    // 64000 f  (256000 B)
    __bf16* enc_bf = (__bf16*)(ws + 272384);                  // A*DE bf16 (131072 B)
    __bf16* att_bf = (__bf16*)(ws + 403456);                  // A*FN bf16 (8192 B)
    float*  ctx_un = (float*)(ws + 411648);                   // 16384 f  (65536 B)
    float*  denom  = (float*)(ws + 477184);                   // 32 f

    prep_kernel<<<209, 256, 0, stream>>>(enc_w, att_w, input_dec, dec_w, att_b,
                                         enc_bf, att_bf, pdec, ctx_un);

    dim3 sgrid((T_ + BT - 1) / BT, B_);
    score_kernel<<<sgrid, 1024, 0, stream>>>(input_enc, enc_bf, prev_att, conv_w,
                                             att_bf, pdec, out_w, enc_lengths,
                                             wbuf, ctx_un, denom);

    finalize_kernel<<<80, 256, 0, stream>>>(wbuf, ctx_un, denom, out);
}

// Round 5
// 224.873 us; speedup vs baseline: 1.0697x; 1.0697x over previous
//
#include <hip/hip_runtime.h>
#include <hip/hip_bf16.h>
#include <math.h>

#define B_ 32
#define T_ 2000
#define DE_ 512
#define DD_ 1024
#define A_ 128
#define FN_ 32
#define FS_ 16
#define KW_ (2*FS_+1)   // 33

typedef __bf16 bf16x8 __attribute__((ext_vector_type(8)));
typedef __bf16 bf16x4 __attribute__((ext_vector_type(4)));
typedef float f32x4 __attribute__((ext_vector_type(4)));

#define BT 64            // t-rows per score block
#define LSTR 40          // loc tile LDS stride (bf16)

// async global->LDS, 16 B per lane; dest = lds base (wave-uniform) + lane*16
__device__ __forceinline__ void load_lds16(const void* g, void* l) {
    __builtin_amdgcn_global_load_lds(
        (const __attribute__((address_space(1))) unsigned int*)g,
        (__attribute__((address_space(3))) unsigned int*)l, 16, 0, 0);
}

__device__ __forceinline__ bf16x8 cvt8v(f32x4 x, f32x4 y) {
    bf16x8 o;
    o[0] = (__bf16)x[0]; o[1] = (__bf16)x[1]; o[2] = (__bf16)x[2]; o[3] = (__bf16)x[3];
    o[4] = (__bf16)y[0]; o[5] = (__bf16)y[1]; o[6] = (__bf16)y[2]; o[7] = (__bf16)y[3];
    return o;
}

// ---------------------------------------------------------------------------
// Kernel 1: prep.
//  blocks   0..63 : enc_w/att_w fp32->bf16
//  blocks  64..191: pdec[b][a] = att_b[a] + input_dec[b] . dec_w[a]
//  blocks 192..208: zero ctx_un (16384 f) + denom (32 f)
// ---------------------------------------------------------------------------
__global__ __launch_bounds__(256) void prep_kernel(
    const float* __restrict__ enc_w, const float* __restrict__ att_w,
    const float* __restrict__ input_dec, const float* __restrict__ dec_w,
    const float* __restrict__ att_b,
    __bf16* __restrict__ enc_bf, __bf16* __restrict__ att_bf,
    float* __restrict__ pdec, float* __restrict__ ctx_un /* denom follows */)
{
    int bx = blockIdx.x, tid = threadIdx.x;
    if (bx < 64) {
        int i = bx * 256 + tid;                         // float4 index
        float4 v = ((const float4*)enc_w)[i];
        bf16x4 o;
        o[0] = (__bf16)v.x; o[1] = (__bf16)v.y; o[2] = (__bf16)v.z; o[3] = (__bf16)v.w;
        *(bf16x4*)(enc_bf + (size_t)i * 4) = o;
        if (i < (A_ * FN_) / 4) {
            float4 w = ((const float4*)att_w)[i];
            bf16x4 p;
            p[0] = (__bf16)w.x; p[1] = (__bf16)w.y; p[2] = (__bf16)w.z; p[3] = (__bf16)w.w;
            *(bf16x4*)(att_bf + (size_t)i * 4) = p;
        }
    } else if (bx < 192) {
        int pb = bx - 64;                               // 0..127
        int b  = pb >> 2;
        int a0 = (pb & 3) * 32;
        int al = tid >> 3;                              // 0..31
        int kg = tid & 7;                               // 0..7
        int a  = a0 + al;
        const float4* w = (const float4*)(dec_w + (size_t)a * DD_);
        const float4* x = (const float4*)(input_dec + (size_t)b * DD_);
        float acc = 0.f;
        #pragma unroll 8
        for (int j = 0; j < 32; j++) {
            int i4 = kg + j * 8;
            float4 wv = w[i4], xv = x[i4];
            acc += wv.x * xv.x + wv.y * xv.y + wv.z * xv.z + wv.w * xv.w;
        }
        acc += __shfl_xor(acc, 1, 64);
        acc += __shfl_xor(acc, 2, 64);
        acc += __shfl_xor(acc, 4, 64);
        if (kg == 0) pdec[b * A_ + a] = acc + att_b[a];
    } else {
        int idx = (bx - 192) * 256 + tid;               // float4 index
        if (idx < (B_ * DE_ + B_) / 4 + 1)              // 16416 floats -> 4104 f4
            ((float4*)ctx_un)[idx] = make_float4(0.f, 0.f, 0.f, 0.f);
    }
}

// ---------------------------------------------------------------------------
// Kernel 2: score + context partials. One block = (b, 64 t-rows), 256 thr.
// BOTH operands staged via global_load_lds (cannot be register-sunk by the
// compiler -> in-flight DMA depth is guaranteed structurally): A (input_enc
// fp32 64x64 chunk, XOR-16 source swizzle) and B (enc_bf, XOR-8 swizzle),
// double-buffered, 2-deep prefetch, raw s_barrier + COUNTED s_waitcnt
// vmcnt(8) (T3+T4; never vmcnt(0) in steady state). Each K-step issues
// exactly 8 DMAs (4 A + 4 B); vmcnt(8) after issuing step it+2 waits
// precisely for step it+1. A-frags are ds_read from LDS and cvt'd to bf16:
// same values, same MFMA order as before -> bit-identical output.
// Conv register-blocked. Max-free softmax: w = exp(score - M),
// M = sum|out_w|. Block accumulates its 64x512 tile into ctx_un + denom.
// ---------------------------------------------------------------------------
__global__ __launch_bounds__(256, 2) void score_kernel(
    const float* __restrict__ input_enc, const __bf16* __restrict__ enc_bf,
    const float* __restrict__ prev_att,  const float* __restrict__ conv_w,
    const __bf16* __restrict__ att_bf,   const float* __restrict__ pdec,
    const float* __restrict__ out_w,     const int* __restrict__ lengths,
    float* __restrict__ wbuf, float* __restrict__ ctx_un,
    float* __restrict__ denom)
{
    __shared__ __align__(16) char At[2][16384];  // A dbuf: 64 rows x 64 f32, XOR16-swz
    __shared__ __align__(16) char Bt[2][16384];  // B dbuf: 128 rows x 64 bf16, XOR8-swz
    __shared__ __align__(16) float pa_s[BT + 2 * FS_];
    __shared__ __align__(16) __bf16 loc_s[BT * LSTR];
    __shared__ float w_s[BT];

    const int tid  = threadIdx.x;
    const int lane = tid & 63;
    const int wv   = tid >> 6;
    const int b  = blockIdx.y;
    const int t0 = blockIdx.x * BT;
    const int len = lengths[b];

    // ---- DMA issue: 4 A-loads + 4 B-loads per thread per K-step ----
    auto issueA = [&](int kc, int bufi) {
        #pragma unroll
        for (int j = 0; j < 4; j++) {
            int s  = j * 256 + tid;
            int r  = s >> 4;                     // row 0..63
            int q  = s & 15;                     // phys 16B slot in 256B row
            int cl = q ^ (r & 15);               // XOR-16 swizzle (source side)
            int t  = t0 + r; if (t > T_ - 1) t = T_ - 1;
            load_lds16(input_enc + ((size_t)(b * T_ + t)) * DE_ + kc + cl * 4,
                       At[bufi] + j * 4096 + wv * 1024);
        }
    };
    auto issueB = [&](int kc, int bufi) {
        #pragma unroll
        for (int j = 0; j < 4; j++) {
            int s  = j * 256 + tid;
            int r  = s >> 3;                     // row 0..127
            int cp = s & 7;
            int c  = cp ^ (r & 7);               // XOR-8 swizzle (source side)
            load_lds16(enc_bf + (size_t)r * DE_ + kc + c * 8,
                       Bt[bufi] + j * 4096 + wv * 1024);
        }
    };

    // issue chunks 0 and 1 immediately (latency covered by pa/conv phase)
    issueA(0, 0);  issueB(0, 0);
    issueA(64, 1); issueB(64, 1);

    // conv weights for this thread's filter f: direct from global (L1-hot)
    const int f    = tid & 31;
    const int rblk = tid >> 5;                   // 0..7 -> rows rblk*8..rblk*8+7
    float cwr[KW_];
    #pragma unroll
    for (int k = 0; k < KW_; k++) cwr[k] = conv_w[f * KW_ + k];

    if (tid < BT + 2 * FS_) {
        int t = t0 - FS_ + tid;
        pa_s[tid] = (t >= 0 && t < T_) ? prev_att[b * T_ + t] : 0.f;
    }
    __syncthreads();                             // pa_s ready (also drains DMAs 0,1)

    {   // conv -> loc (bf16), register-blocked: 8 consecutive rows per thread
        float par[40];
        #pragma unroll
        for (int j = 0; j < 10; j++)
            *(float4*)&par[j * 4] = *(const float4*)&pa_s[rblk * 8 + j * 4];
        float accv[8] = {0.f, 0.f, 0.f, 0.f, 0.f, 0.f, 0.f, 0.f};
        #pragma unroll
        for (int k = 0; k < KW_; k++) {
            float c = cwr[k];
            #pragma unroll
            for (int j = 0; j < 8; j++) accv[j] += par[j + k] * c;
        }
        #pragma unroll
        for (int j = 0; j < 8; j++)
            loc_s[(rblk * 8 + j) * LSTR + f] = (__bf16)accv[j];
    }
    __syncthreads();                             // loc_s ready

    const int col  = lane & 15;
    const int grp  = lane >> 4;
    const int rowb = wv * 16 + col;              // 0..63
    const int sw   = (col & 7);                  // B-read swizzle key
    const int key  = rowb & 15;                  // A-read swizzle key

    f32x4 acc[8];
    const f32x4 zero = (f32x4){0.f, 0.f, 0.f, 0.f};

    {   // loc-projection MFMA (K=32=FN)
        bf16x8 afrag = *(const bf16x8*)(loc_s + rowb * LSTR + grp * 8);
        #pragma unroll
        for (int i = 0; i < 8; i++) {
            bf16x8 bfrag = *(const bf16x8*)(att_bf + (size_t)(i * 16 + col) * FN_ + grp * 8);
            acc[i] = __builtin_amdgcn_mfma_f32_16x16x32_bf16(afrag, bfrag, zero, 0, 0, 0);
        }
    }

    auto compute = [&](const char* Ab, const char* Bb) {
        f32x4 v0 = *(const f32x4*)(Ab + rowb * 256 + ((grp * 2)     ^ key) * 16);
        f32x4 v1 = *(const f32x4*)(Ab + rowb * 256 + ((grp * 2 + 1) ^ key) * 16);
        f32x4 v2 = *(const f32x4*)(Ab + rowb * 256 + ((8 + grp * 2)     ^ key) * 16);
        f32x4 v3 = *(const f32x4*)(Ab + rowb * 256 + ((8 + grp * 2 + 1) ^ key) * 16);
        bf16x8 af0 = cvt8v(v0, v1);              // cols kc+grp*8   .. +8
        bf16x8 af1 = cvt8v(v2, v3);              // cols kc+32+grp*8.. +8
        #pragma unroll
        for (int i = 0; i < 8; i++) {
            bf16x8 bfrag = *(const bf16x8*)(Bb + (i * 16 + col) * 128 + ((grp ^ sw) * 16));
            acc[i] = __builtin_amdgcn_mfma_f32_16x16x32_bf16(af0, bfrag, acc[i], 0, 0, 0);
        }
        #pragma unroll
        for (int i = 0; i < 8; i++) {
            bf16x8 bfrag = *(const bf16x8*)(Bb + (i * 16 + col) * 128 + (((4 + grp) ^ sw) * 16));
            acc[i] = __builtin_amdgcn_mfma_f32_16x16x32_bf16(af1, bfrag, acc[i], 0, 0, 0);
        }
    };

    // ---- K-loop: 2-deep global_load_lds pipeline, counted vmcnt ----
    #pragma unroll
    for (int it = 0; it < 8; ++it) {
        compute(At[it & 1], Bt[it & 1]);
        if (it == 7) break;
        __builtin_amdgcn_s_barrier();            // all waves done reading buf[it&1]
        if (it + 2 < 8) {
            issueA((it + 2) * 64, it & 1);       // overwrite just-consumed buffer
            issueB((it + 2) * 64, it & 1);
            asm volatile("s_waitcnt vmcnt(8)" ::: "memory");  // step it+1 done
        } else {
            asm volatile("s_waitcnt vmcnt(0)" ::: "memory");  // drain tail
        }
        __builtin_amdgcn_s_barrier();            // buf[(it+1)&1] visible to all
        __builtin_amdgcn_sched_barrier(0);       // pin phase boundary
    }

    // epilogue: s = tanh(acc + bias) . out_w over a; M = sum|out_w|
    float s[4] = {0.f, 0.f, 0.f, 0.f};
    float Mabs = 0.f;
    #pragma unroll
    for (int i = 0; i < 8; i++) {
        int a = i * 16 + col;
        float ow = out_w[a];
        Mabs += fabsf(ow);
        float bias = pdec[b * A_ + a];
        #pragma unroll
        for (int r = 0; r < 4; r++) {
            float v = acc[i][r] + bias;
            v = fminf(fmaxf(v, -15.f), 15.f);
            float e = __expf(2.f * v);
            s[r] += ow * ((e - 1.f) / (e + 1.f));
        }
    }
    #pragma unroll
    for (int r = 0; r < 4; r++) {
        s[r] += __shfl_xor(s[r], 1, 64);
        s[r] += __shfl_xor(s[r], 2, 64);
        s[r] += __shfl_xor(s[r], 4, 64);
        s[r] += __shfl_xor(s[r], 8, 64);
    }
    Mabs += __shfl_xor(Mabs, 1, 64);
    Mabs += __shfl_xor(Mabs, 2, 64);
    Mabs += __shfl_xor(Mabs, 4, 64);
    Mabs += __shfl_xor(Mabs, 8, 64);    // same value & rounding in every wave

    if (col == 0) {
        #pragma unroll
        for (int r = 0; r < 4; r++) {
            int rl = wv * 16 + grp * 4 + r;
            int t = t0 + rl;
            float w = 0.f;
            if (t < len) w = __expf(s[r] - Mabs);
            w_s[rl] = w;
            if (t < T_) wbuf[b * T_ + t] = w;
        }
    }
    __syncthreads();

    // denominator partial (wave 0)
    if (tid < 64) {
        float w = w_s[tid];
        w += __shfl_xor(w, 1, 64);
        w += __shfl_xor(w, 2, 64);
        w += __shfl_xor(w, 4, 64);
        w += __shfl_xor(w, 8, 64);
        w += __shfl_xor(w, 16, 64);
        w += __shfl_xor(w, 32, 64);
        if (tid == 0) atomicAdd(&denom[b], w);
    }

    // context partial: tile rows are L2/L3-hot from the GEMM reads
    int n_eff = len - t0;
    if (n_eff > BT) n_eff = BT;
    if (n_eff > 0) {
        int d0 = tid * 2;
        const float* ebase = input_enc + ((size_t)(b * T_ + t0)) * DE_ + d0;
        float cx = 0.f, cy = 0.f;
        #pragma unroll 8
        for (int t = 0; t < n_eff; t++) {
            float w = w_s[t];
            float2 v = *(const float2*)(ebase + (size_t)t * DE_);
            cx += w * v.x;
            cy += w * v.y;
        }
        atomicAdd(&ctx_un[b * DE_ + d0 + 0], cx);
        atomicAdd(&ctx_un[b * DE_ + d0 + 1], cy);
    }
}

// ---------------------------------------------------------------------------
// Kernel 3: finalize. blocks 0..63: att = wbuf/denom; 64..79: ctx = ctx_un/denom
// ---------------------------------------------------------------------------
__global__ __launch_bounds__(256) void finalize_kernel(
    const float* __restrict__ wbuf, const float* __restrict__ ctx_un,
    const float* __restrict__ denom, float* __restrict__ out)
{
    int bx = blockIdx.x, tid = threadIdx.x;
    if (bx < 64) {
        int i4 = bx * 256 + tid;
        if (i4 < (B_ * T_) / 4) {
            int b = i4 / (T_ / 4);
            float inv = 1.f / denom[b];
            float4 w = ((const float4*)wbuf)[i4];
            w.x *= inv; w.y *= inv; w.z *= inv; w.w *= inv;
            ((float4*)(out + B_ * DE_))[i4] = w;
        }
    } else {
        int j = (bx - 64) * 256 + tid;          // 0..4095
        int b = j / (DE_ / 4);
        float inv = 1.f / denom[b];
        float4 c = ((const float4*)ctx_un)[j];
        c.x *= inv; c.y *= inv; c.z *= inv; c.w *= inv;
        ((float4*)out)[j] = c;
    }
}

// ---------------------------------------------------------------------------
extern "C" void kernel_launch(void* const* d_in, const int* in_sizes, int n_in,
                              void* d_out, int out_size, void* d_ws, size_t ws_size,
                              hipStream_t stream)
{
    const float* input_enc   = (const float*)d_in[0];
    const int*   enc_lengths = (const int*)d_in[1];
    const float* input_dec   = (const float*)d_in[2];
    const float* prev_att    = (const float*)d_in[3];
    const float* conv_w      = (const float*)d_in[4];
    const float* enc_w       = (const float*)d_in[5];
    const float* dec_w       = (const float*)d_in[6];
    const float* att_w       = (const float*)d_in[7];
    const float* att_b       = (const float*)d_in[8];
    const float* out_w       = (const float*)d_in[9];

    float* out = (float*)d_out;                 // [0:B*DE) context, [B*DE:) att_weight
    char* ws = (char*)d_ws;
    float*  pdec   = (float*)ws;                              // 4096 f   (16384 B)
    float*  wbuf   = (float*)(ws + 16384);                    // 64000 f  (256000 B)
    __bf16* enc_bf = (__bf16*)(ws + 272384);                  // A*DE bf16 (131072 B)
    __bf16* att_bf = (__bf16*)(ws + 403456);                  // A*FN bf16 (8192 B)
    float*  ctx_un = (float*)(ws + 411648);                   // 16384 f  (65536 B)
    float*  denom  = (float*)(ws + 477184);                   // 32 f

    prep_kernel<<<209, 256, 0, stream>>>(enc_w, att_w, input_dec, dec_w, att_b,
                                         enc_bf, att_bf, pdec, ctx_un);

    dim3 sgrid((T_ + BT - 1) / BT, B_);
    score_kernel<<<sgrid, 256, 0, stream>>>(input_enc, enc_bf, prev_att, conv_w,
                                            att_bf, pdec, out_w, enc_lengths,
                                            wbuf, ctx_un, denom);

    finalize_kernel<<<80, 256, 0, stream>>>(wbuf, ctx_un, denom, out);
}

// Round 6
// 223.709 us; speedup vs baseline: 1.0753x; 1.0052x over previous
//
#include <hip/hip_runtime.h>
#include <hip/hip_bf16.h>
#include <math.h>

#define B_ 32
#define T_ 2000
#define DE_ 512
#define DD_ 1024
#define A_ 128
#define FN_ 32
#define FS_ 16
#define KW_ (2*FS_+1)   // 33

typedef __bf16 bf16x8 __attribute__((ext_vector_type(8)));
typedef __bf16 bf16x4 __attribute__((ext_vector_type(4)));
typedef float f32x4 __attribute__((ext_vector_type(4)));

#define BT 64            // t-rows per score block
#define KC 32            // K columns per staged chunk (16 iterations)
#define LSTR 40          // loc tile LDS stride (bf16)

// async global->LDS, 16 B per lane; dest = lds base (wave-uniform) + lane*16
__device__ __forceinline__ void load_lds16(const void* g, void* l) {
    __builtin_amdgcn_global_load_lds(
        (const __attribute__((address_space(1))) unsigned int*)g,
        (__attribute__((address_space(3))) unsigned int*)l, 16, 0, 0);
}

__device__ __forceinline__ bf16x8 cvt8v(f32x4 x, f32x4 y) {
    bf16x8 o;
    o[0] = (__bf16)x[0]; o[1] = (__bf16)x[1]; o[2] = (__bf16)x[2]; o[3] = (__bf16)x[3];
    o[4] = (__bf16)y[0]; o[5] = (__bf16)y[1]; o[6] = (__bf16)y[2]; o[7] = (__bf16)y[3];
    return o;
}

// ---------------------------------------------------------------------------
// Kernel 1: prep.
//  blocks   0..63 : enc_w/att_w fp32->bf16
//  blocks  64..191: pdec[b][a] = att_b[a] + input_dec[b] . dec_w[a]
//  blocks 192..208: zero ctx_un (16384 f) + denom (32 f)
// ---------------------------------------------------------------------------
__global__ __launch_bounds__(256) void prep_kernel(
    const float* __restrict__ enc_w, const float* __restrict__ att_w,
    const float* __restrict__ input_dec, const float* __restrict__ dec_w,
    const float* __restrict__ att_b,
    __bf16* __restrict__ enc_bf, __bf16* __restrict__ att_bf,
    float* __restrict__ pdec, float* __restrict__ ctx_un /* denom follows */)
{
    int bx = blockIdx.x, tid = threadIdx.x;
    if (bx < 64) {
        int i = bx * 256 + tid;                         // float4 index
        float4 v = ((const float4*)enc_w)[i];
        bf16x4 o;
        o[0] = (__bf16)v.x; o[1] = (__bf16)v.y; o[2] = (__bf16)v.z; o[3] = (__bf16)v.w;
        *(bf16x4*)(enc_bf + (size_t)i * 4) = o;
        if (i < (A_ * FN_) / 4) {
            float4 w = ((const float4*)att_w)[i];
            bf16x4 p;
            p[0] = (__bf16)w.x; p[1] = (__bf16)w.y; p[2] = (__bf16)w.z; p[3] = (__bf16)w.w;
            *(bf16x4*)(att_bf + (size_t)i * 4) = p;
        }
    } else if (bx < 192) {
        int pb = bx - 64;                               // 0..127
        int b  = pb >> 2;
        int a0 = (pb & 3) * 32;
        int al = tid >> 3;                              // 0..31
        int kg = tid & 7;                               // 0..7
        int a  = a0 + al;
        const float4* w = (const float4*)(dec_w + (size_t)a * DD_);
        const float4* x = (const float4*)(input_dec + (size_t)b * DD_);
        float acc = 0.f;
        #pragma unroll 8
        for (int j = 0; j < 32; j++) {
            int i4 = kg + j * 8;
            float4 wv = w[i4], xv = x[i4];
            acc += wv.x * xv.x + wv.y * xv.y + wv.z * xv.z + wv.w * xv.w;
        }
        acc += __shfl_xor(acc, 1, 64);
        acc += __shfl_xor(acc, 2, 64);
        acc += __shfl_xor(acc, 4, 64);
        if (kg == 0) pdec[b * A_ + a] = acc + att_b[a];
    } else {
        int idx = (bx - 192) * 256 + tid;               // float4 index
        if (idx < (B_ * DE_ + B_) / 4 + 1)              // 16416 floats -> 4104 f4
            ((float4*)ctx_un)[idx] = make_float4(0.f, 0.f, 0.f, 0.f);
    }
}

// ---------------------------------------------------------------------------
// Kernel 2: score + context partials. One block = (b, 64 t-rows), 256 thr.
// Changes vs r5: (1) K-chunk halved to 32 -> LDS 38.5 KB -> 4 blocks/CU =
// 4 waves/SIMD (TLP to hide HBM latency at the vmcnt/barrier waits) AND the
// whole grid is co-resident in ONE round; (2) blocks fully past len early-
// exit (write wbuf zeros, skip all traffic/compute); (3) no sched_barrier.
// Counted-vmcnt DMA pipeline kept: both operands staged via global_load_lds
// (cannot be register-sunk), double-buffered, 2-deep prefetch, raw s_barrier
// + s_waitcnt vmcnt(4) (never 0 in steady state). Each step issues exactly
// 4 DMAs (2 A + 2 B). K accumulation order unchanged -> bit-identical.
// Max-free softmax: w = exp(score - M), M = sum|out_w|. Block accumulates
// its 64x512 tile into ctx_un + denom.
// ---------------------------------------------------------------------------
__global__ __launch_bounds__(256, 4) void score_kernel(
    const float* __restrict__ input_enc, const __bf16* __restrict__ enc_bf,
    const float* __restrict__ prev_att,  const float* __restrict__ conv_w,
    const __bf16* __restrict__ att_bf,   const float* __restrict__ pdec,
    const float* __restrict__ out_w,     const int* __restrict__ lengths,
    float* __restrict__ wbuf, float* __restrict__ ctx_un,
    float* __restrict__ denom)
{
    __shared__ __align__(16) char At[2][8192];   // A dbuf: 64 rows x 32 f32 (128B/row, XOR-8 swz)
    __shared__ __align__(16) char Bt[2][8192];   // B dbuf: 128 rows x 32 bf16 (64B/row, XOR swz)
    __shared__ __align__(16) float pa_s[BT + 2 * FS_];
    __shared__ __align__(16) __bf16 loc_s[BT * LSTR];
    __shared__ float w_s[BT];

    const int tid  = threadIdx.x;
    const int lane = tid & 63;
    const int wv   = tid >> 6;
    const int b  = blockIdx.y;
    const int t0 = blockIdx.x * BT;
    const int len = lengths[b];

    // ---- early exit: block entirely past this utterance's length ----
    if (t0 >= len) {
        if (tid < BT) {
            int t = t0 + tid;
            if (t < T_) wbuf[b * T_ + t] = 0.f;
        }
        return;
    }

    // ---- DMA issue: 2 A-loads + 2 B-loads per thread per K-step ----
    auto issueA = [&](int kc, int bufi) {
        #pragma unroll
        for (int j = 0; j < 2; j++) {
            int s  = j * 256 + tid;              // 0..511
            int r  = s >> 3;                     // row 0..63 (8 x 16B slots/row)
            int q  = s & 7;                      // phys 16B slot
            int cl = q ^ (r & 7);                // XOR-8 swizzle (source side)
            int t  = t0 + r; if (t > T_ - 1) t = T_ - 1;
            load_lds16(input_enc + ((size_t)(b * T_ + t)) * DE_ + kc + cl * 4,
                       At[bufi] + j * 4096 + wv * 1024);
        }
    };
    auto issueB = [&](int kc, int bufi) {
        #pragma unroll
        for (int j = 0; j < 2; j++) {
            int s  = j * 256 + tid;              // 0..511
            int r  = s >> 2;                     // row 0..127 (4 x 16B slots/row)
            int q  = s & 3;                      // phys slot
            int cl = q ^ ((r >> 1) & 3);         // swizzle: 2-way max conflict on read
            load_lds16(enc_bf + (size_t)r * DE_ + kc + cl * 8,
                       Bt[bufi] + j * 4096 + wv * 1024);
        }
    };

    // issue chunks 0 and 1 (latency covered by pa/conv phase)
    issueA(0, 0);   issueB(0, 0);
    issueA(KC, 1);  issueB(KC, 1);

    // conv weights for this thread's filter f: direct from global (L1-hot)
    const int f    = tid & 31;
    const int rblk = tid >> 5;                   // 0..7 -> rows rblk*8..rblk*8+7
    float cwr[KW_];
    #pragma unroll
    for (int k = 0; k < KW_; k++) cwr[k] = conv_w[f * KW_ + k];

    if (tid < BT + 2 * FS_) {
        int t = t0 - FS_ + tid;
        pa_s[tid] = (t >= 0 && t < T_) ? prev_att[b * T_ + t] : 0.f;
    }
    __syncthreads();                             // pa_s ready (drains DMAs 0,1)

    {   // conv -> loc (bf16), register-blocked: 8 consecutive rows per thread
        float par[40];
        #pragma unroll
        for (int j = 0; j < 10; j++)
            *(float4*)&par[j * 4] = *(const float4*)&pa_s[rblk * 8 + j * 4];
        float accv[8] = {0.f, 0.f, 0.f, 0.f, 0.f, 0.f, 0.f, 0.f};
        #pragma unroll
        for (int k = 0; k < KW_; k++) {
            float c = cwr[k];
            #pragma unroll
            for (int j = 0; j < 8; j++) accv[j] += par[j + k] * c;
        }
        #pragma unroll
        for (int j = 0; j < 8; j++)
            loc_s[(rblk * 8 + j) * LSTR + f] = (__bf16)accv[j];
    }
    __syncthreads();                             // loc_s ready

    const int col  = lane & 15;
    const int grp  = lane >> 4;
    const int rowb = wv * 16 + col;              // 0..63
    const int keyA = rowb & 7;                   // A-read swizzle key

    f32x4 acc[8];
    const f32x4 zero = (f32x4){0.f, 0.f, 0.f, 0.f};

    {   // loc-projection MFMA (K=32=FN)
        bf16x8 afrag = *(const bf16x8*)(loc_s + rowb * LSTR + grp * 8);
        #pragma unroll
        for (int i = 0; i < 8; i++) {
            bf16x8 bfrag = *(const bf16x8*)(att_bf + (size_t)(i * 16 + col) * FN_ + grp * 8);
            acc[i] = __builtin_amdgcn_mfma_f32_16x16x32_bf16(afrag, bfrag, zero, 0, 0, 0);
        }
    }

    auto compute = [&](const char* Ab, const char* Bb) {
        f32x4 v0 = *(const f32x4*)(Ab + rowb * 128 + ((grp * 2)     ^ keyA) * 16);
        f32x4 v1 = *(const f32x4*)(Ab + rowb * 128 + ((grp * 2 + 1) ^ keyA) * 16);
        bf16x8 af = cvt8v(v0, v1);               // cols kc+grp*8 .. +8
        #pragma unroll
        for (int i = 0; i < 8; i++) {
            int row = i * 16 + col;
            bf16x8 bfrag = *(const bf16x8*)(Bb + row * 64 + ((grp ^ ((row >> 1) & 3)) * 16));
            acc[i] = __builtin_amdgcn_mfma_f32_16x16x32_bf16(af, bfrag, acc[i], 0, 0, 0);
        }
    };

    // ---- K-loop: 2-deep global_load_lds pipeline, counted vmcnt ----
    #pragma unroll
    for (int it = 0; it < 16; ++it) {
        compute(At[it & 1], Bt[it & 1]);
        if (it == 15) break;
        __builtin_amdgcn_s_barrier();            // all waves done reading buf[it&1]
        if (it + 2 < 16) {
            issueA((it + 2) * KC, it & 1);       // overwrite just-consumed buffer
            issueB((it + 2) * KC, it & 1);
            asm volatile("s_waitcnt vmcnt(4)" ::: "memory");  // step it+1 done
        } else {
            asm volatile("s_waitcnt vmcnt(0)" ::: "memory");  // drain tail
        }
        __builtin_amdgcn_s_barrier();            // buf[(it+1)&1] visible to all
    }

    // epilogue: s = tanh(acc + bias) . out_w over a; M = sum|out_w|
    float s[4] = {0.f, 0.f, 0.f, 0.f};
    float Mabs = 0.f;
    #pragma unroll
    for (int i = 0; i < 8; i++) {
        int a = i * 16 + col;
        float ow = out_w[a];
        Mabs += fabsf(ow);
        float bias = pdec[b * A_ + a];
        #pragma unroll
        for (int r = 0; r < 4; r++) {
            float v = acc[i][r] + bias;
            v = fminf(fmaxf(v, -15.f), 15.f);
            float e = __expf(2.f * v);
            s[r] += ow * ((e - 1.f) / (e + 1.f));
        }
    }
    #pragma unroll
    for (int r = 0; r < 4; r++) {
        s[r] += __shfl_xor(s[r], 1, 64);
        s[r] += __shfl_xor(s[r], 2, 64);
        s[r] += __shfl_xor(s[r], 4, 64);
        s[r] += __shfl_xor(s[r], 8, 64);
    }
    Mabs += __shfl_xor(Mabs, 1, 64);
    Mabs += __shfl_xor(Mabs, 2, 64);
    Mabs += __shfl_xor(Mabs, 4, 64);
    Mabs += __shfl_xor(Mabs, 8, 64);    // same value & rounding in every wave

    if (col == 0) {
        #pragma unroll
        for (int r = 0; r < 4; r++) {
            int rl = wv * 16 + grp * 4 + r;
            int t = t0 + rl;
            float w = 0.f;
            if (t < len) w = __expf(s[r] - Mabs);
            w_s[rl] = w;
            if (t < T_) wbuf[b * T_ + t] = w;
        }
    }
    __syncthreads();

    // denominator partial (wave 0)
    if (tid < 64) {
        float w = w_s[tid];
        w += __shfl_xor(w, 1, 64);
        w += __shfl_xor(w, 2, 64);
        w += __shfl_xor(w, 4, 64);
        w += __shfl_xor(w, 8, 64);
        w += __shfl_xor(w, 16, 64);
        w += __shfl_xor(w, 32, 64);
        if (tid == 0) atomicAdd(&denom[b], w);
    }

    // context partial: tile rows are L2/L3-hot from the GEMM reads
    int n_eff = len - t0;
    if (n_eff > BT) n_eff = BT;
    if (n_eff > 0) {
        int d0 = tid * 2;
        const float* ebase = input_enc + ((size_t)(b * T_ + t0)) * DE_ + d0;
        float cx = 0.f, cy = 0.f;
        #pragma unroll 8
        for (int t = 0; t < n_eff; t++) {
            float w = w_s[t];
            float2 v = *(const float2*)(ebase + (size_t)t * DE_);
            cx += w * v.x;
            cy += w * v.y;
        }
        atomicAdd(&ctx_un[b * DE_ + d0 + 0], cx);
        atomicAdd(&ctx_un[b * DE_ + d0 + 1], cy);
    }
}

// ---------------------------------------------------------------------------
// Kernel 3: finalize. blocks 0..63: att = wbuf/denom; 64..79: ctx = ctx_un/denom
// ---------------------------------------------------------------------------
__global__ __launch_bounds__(256) void finalize_kernel(
    const float* __restrict__ wbuf, const float* __restrict__ ctx_un,
    const float* __restrict__ denom, float* __restrict__ out)
{
    int bx = blockIdx.x, tid = threadIdx.x;
    if (bx < 64) {
        int i4 = bx * 256 + tid;
        if (i4 < (B_ * T_) / 4) {
            int b = i4 / (T_ / 4);
            float inv = 1.f / denom[b];
            float4 w = ((const float4*)wbuf)[i4];
            w.x *= inv; w.y *= inv; w.z *= inv; w.w *= inv;
            ((float4*)(out + B_ * DE_))[i4] = w;
        }
    } else {
        int j = (bx - 64) * 256 + tid;          // 0..4095
        int b = j / (DE_ / 4);
        float inv = 1.f / denom[b];
        float4 c = ((const float4*)ctx_un)[j];
        c.x *= inv; c.y *= inv; c.z *= inv; c.w *= inv;
        ((float4*)out)[j] = c;
    }
}

// ---------------------------------------------------------------------------
extern "C" void kernel_launch(void* const* d_in, const int* in_sizes, int n_in,
                              void* d_out, int out_size, void* d_ws, size_t ws_size,
                              hipStream_t stream)
{
    const float* input_enc   = (const float*)d_in[0];
    const int*   enc_lengths = (const int*)d_in[1];
    const float* input_dec   = (const float*)d_in[2];
    const float* prev_att    = (const float*)d_in[3];
    const float* conv_w      = (const float*)d_in[4];
    const float* enc_w       = (const float*)d_in[5];
    const float* dec_w       = (const float*)d_in[6];
    const float* att_w       = (const float*)d_in[7];
    const float* att_b       = (const float*)d_in[8];
    const float* out_w       = (const float*)d_in[9];

    float* out = (float*)d_out;                 // [0:B*DE) context, [B*DE:) att_weight
    char* ws = (char*)d_ws;
    float*  pdec   = (float*)ws;                              // 4096 f   (16384 B)
    float*  wbuf   = (float*)(ws + 16384);                    // 64000 f  (256000 B)
    __bf16* enc_bf = (__bf16*)(ws + 272384);                  // A*DE bf16 (131072 B)
    __bf16* att_bf = (__bf16*)(ws + 403456);                  // A*FN bf16 (8192 B)
    float*  ctx_un = (float*)(ws + 411648);                   // 16384 f  (65536 B)
    float*  denom  = (float*)(ws + 477184);                   // 32 f

    prep_kernel<<<209, 256, 0, stream>>>(enc_w, att_w, input_dec, dec_w, att_b,
                                         enc_bf, att_bf, pdec, ctx_un);

    dim3 sgrid((T_ + BT - 1) / BT, B_);
    score_kernel<<<sgrid, 256, 0, stream>>>(input_enc, enc_bf, prev_att, conv_w,
                                            att_bf, pdec, out_w, enc_lengths,
                                            wbuf, ctx_un, denom);

    finalize_kernel<<<80, 256, 0, stream>>>(wbuf, ctx_un, denom, out);
}